// Round 9
// baseline (244.925 us; speedup 1.0000x reference)
//
#include <hip/hip_runtime.h>

// WKV (RWKV v4), fully fused single kernel, 512-thread blocks x 4/CU.
//
// Residency calibration (measured): regsPerBlock=131072/CU.
//   R7/R8: 1024-thr @ VGPR64 -> 2*65536 = exactly 131072 does NOT fit
//          -> 1 block/CU = 16 waves -> occ 35%, 94-99us.
//   R6:    1024-thr @ VGPR32 -> 2 blocks, occ 79% (but spilled).
//   R4:    512-thr under (512,2) cap128 -> compiler naturally picks 52
//          VGPR, no spill.
// This round reuses R4's measured codegen shape (512-thr block, cap 128)
// and gets 32 waves/CU by quadrupling blocks: CTILE 32->16 =>
// grid = B*C/16 = 1024 blocks = 4 blocks/CU (4*512*52 = 106K regs < 131K,
// LDS 24KB*4 = 96KB < 160KB).
//
// Block = 512 threads = 128 chunks x 4 channel-group threads; owns one
// (batch b, 16-channel tile).
//   Phase 1: stream chunk (CHL=8 rows, BATCH=4) -> local state.
//   Phase 2: Hillis-Steele exclusive scan over 128 chunk states in LDS.
//   Phase 3: re-stream chunk (L2/L3-resident) and emit y non-temporally.
//
// 16-ch tiles make wave loads 16x64B half-lines; the other half of each
// 128B line belongs to the adjacent tile. Pair-swizzle: tile-pair
// (2t,2t+1) placed at grid slots p and p+512 -> same XCD under
// round-robin (512 % 8 == 0) -> one L2 fetches the full line once.
// Tripwire: FETCH >> 140MB means this failed (cross-XCD double fetch).
//
// All state in log2 domain (w,u,k pre-scaled by log2 e): every exponential
// is a bare v_exp_f32.

#define T_FIX  1024
#define NCH    128
#define CHL    (T_FIX / NCH)      // 8
#define BATCH  4
#define CTILE  16                 // channels per block (64B half-lines)
#define CGT    (CTILE / 4)        // 4 channel-group threads
#define NTHR   (NCH * CGT)        // 512
#define L2E    1.4426950408889634f

typedef float vfloat4 __attribute__((ext_vector_type(4)));

#define F4TOA(a, f) { a[0] = (f).x; a[1] = (f).y; a[2] = (f).z; a[3] = (f).w; }

__device__ __forceinline__ void wkv_step2(float& aa, float& bb, float& pp,
                                          float w2, float k2, float vt)
{
    float ww2 = pp + w2;
    float q2  = fmaxf(ww2, k2);
    float e1  = exp2f(ww2 - q2);
    float e2  = exp2f(k2 - q2);
    aa = fmaf(e1, aa, e2 * vt);
    bb = fmaf(e1, bb, e2);
    pp = q2;
}

__global__ __launch_bounds__(NTHR, 2)
void wkv_fused(const float* __restrict__ td,
               const float* __restrict__ tf,
               const float* __restrict__ k,
               const float* __restrict__ v,
               float* __restrict__ y,
               int B, int C)
{
    __shared__ float4 a_s[NTHR];
    __shared__ float4 b_s[NTHR];
    __shared__ float4 p_s[NTHR];

    const int tid = threadIdx.x;
    const int cg  = tid & (CGT - 1);     // channel group within tile
    const int j   = tid >> 2;            // chunk index 0..127

    // pair-swizzle: slot s in [0,half) is member 0 of pair s; slot
    // s in [half,G) is member 1 of pair s-half. orig = pair*2 + member.
    const int G    = gridDim.x;
    const int half = G >> 1;
    const int m    = (blockIdx.x >= half) ? 1 : 0;
    const int orig = ((blockIdx.x - m * half) << 1) + m;

    const int tiles = C / CTILE;
    const int b    = orig / tiles;
    const int tile = orig % tiles;
    const int c    = tile * CTILE + (cg << 2);

    float4 tdv = *(const float4*)(td + c);
    float4 tfv = *(const float4*)(tf + c);
    float w2[4] = { -__expf(tdv.x) * L2E, -__expf(tdv.y) * L2E,
                    -__expf(tdv.z) * L2E, -__expf(tdv.w) * L2E };
    float u2[4] = { tfv.x * L2E, tfv.y * L2E, tfv.z * L2E, tfv.w * L2E };

    const size_t base = ((size_t)b * T_FIX + (size_t)j * CHL) * C + c;
    const float* kp = k + base;
    const float* vp = v + base;
    float*       yp = y + base;

    // ---------------- phase 1: local chunk state (streamed) ----------------
    float aa[4] = {0.f, 0.f, 0.f, 0.f};
    float bb[4] = {0.f, 0.f, 0.f, 0.f};
    float pp[4] = {-1e38f, -1e38f, -1e38f, -1e38f};

    for (int tb = 0; tb < CHL; tb += BATCH) {
        float4 kb[BATCH], vb[BATCH];
        #pragma unroll
        for (int i = 0; i < BATCH; ++i) {
            kb[i] = *(const float4*)(kp + (size_t)(tb + i) * C);
            vb[i] = *(const float4*)(vp + (size_t)(tb + i) * C);
        }
        #pragma unroll
        for (int i = 0; i < BATCH; ++i) {
            float ka[4], va[4];
            F4TOA(ka, kb[i]); F4TOA(va, vb[i]);
            #pragma unroll
            for (int cc = 0; cc < 4; ++cc)
                wkv_step2(aa[cc], bb[cc], pp[cc], w2[cc], ka[cc] * L2E, va[cc]);
        }
    }

    a_s[tid] = make_float4(aa[0], aa[1], aa[2], aa[3]);
    b_s[tid] = make_float4(bb[0], bb[1], bb[2], bb[3]);
    p_s[tid] = make_float4(pp[0], pp[1], pp[2], pp[3]);
    __syncthreads();

    // ---------------- phase 2: Hillis-Steele scan over chunks ----------------
    #pragma unroll
    for (int d = 1; d < NCH; d <<= 1) {
        float pa[4], pb[4], pm[4];
        const bool act = (j >= d);
        if (act) {
            float4 xa = a_s[tid - CGT * d];
            float4 xb = b_s[tid - CGT * d];
            float4 xp = p_s[tid - CGT * d];
            F4TOA(pa, xa); F4TOA(pb, xb); F4TOA(pm, xp);
        }
        __syncthreads();
        if (act) {
            const float Ld = (float)(d * CHL);   // steps the own value spans
            #pragma unroll
            for (int cc = 0; cc < 4; ++cc) {
                float ppd = fmaf(Ld, w2[cc], pm[cc]);   // decay predecessor
                float pn  = fmaxf(ppd, pp[cc]);
                float ea  = exp2f(ppd - pn);
                float eb  = exp2f(pp[cc] - pn);
                aa[cc] = fmaf(ea, pa[cc], eb * aa[cc]);
                bb[cc] = fmaf(ea, pb[cc], eb * bb[cc]);
                pp[cc] = pn;
            }
            a_s[tid] = make_float4(aa[0], aa[1], aa[2], aa[3]);
            b_s[tid] = make_float4(bb[0], bb[1], bb[2], bb[3]);
            p_s[tid] = make_float4(pp[0], pp[1], pp[2], pp[3]);
        }
        __syncthreads();
    }

    // exclusive prefix for this chunk = inclusive value of chunk j-1
    if (j > 0) {
        float4 xa = a_s[tid - CGT];
        float4 xb = b_s[tid - CGT];
        float4 xp = p_s[tid - CGT];
        F4TOA(aa, xa); F4TOA(bb, xb); F4TOA(pp, xp);
    } else {
        #pragma unroll
        for (int cc = 0; cc < 4; ++cc) { aa[cc] = 0.f; bb[cc] = 0.f; pp[cc] = -1e38f; }
    }

    // ---------------- phase 3: re-stream chunk, emit y ----------------
    for (int tb = 0; tb < CHL; tb += BATCH) {
        float4 kb[BATCH], vb[BATCH];
        #pragma unroll
        for (int i = 0; i < BATCH; ++i) {
            kb[i] = *(const float4*)(kp + (size_t)(tb + i) * C);
            vb[i] = *(const float4*)(vp + (size_t)(tb + i) * C);
        }
        #pragma unroll
        for (int i = 0; i < BATCH; ++i) {
            float ka[4], va[4], ya[4];
            F4TOA(ka, kb[i]); F4TOA(va, vb[i]);
            #pragma unroll
            for (int cc = 0; cc < 4; ++cc) {
                float k2 = ka[cc] * L2E;
                float ww = u2[cc] + k2;
                float q  = fmaxf(pp[cc], ww);
                float e1 = exp2f(pp[cc] - q);
                float e2 = exp2f(ww - q);
                ya[cc] = __fdividef(fmaf(e1, aa[cc], e2 * va[cc]),
                                    fmaf(e1, bb[cc], e2));
                wkv_step2(aa[cc], bb[cc], pp[cc], w2[cc], k2, va[cc]);
            }
            vfloat4 yo = { ya[0], ya[1], ya[2], ya[3] };
            __builtin_nontemporal_store(yo, (vfloat4*)(yp + (size_t)(tb + i) * C));
        }
    }
}

extern "C" void kernel_launch(void* const* d_in, const int* in_sizes, int n_in,
                              void* d_out, int out_size, void* d_ws, size_t ws_size,
                              hipStream_t stream)
{
    const float* td = (const float*)d_in[3];
    const float* tf = (const float*)d_in[4];
    const float* k  = (const float*)d_in[5];
    const float* v  = (const float*)d_in[6];
    float*       y  = (float*)d_out;

    const int C   = in_sizes[3];
    const int BTC = in_sizes[5];
    const int B   = BTC / (T_FIX * C);

    const int grid = B * (C / CTILE);   // 1024 for B=8, C=2048
    wkv_fused<<<grid, NTHR, 0, stream>>>(td, tf, k, v, y, B, C);
}

// Round 10
// 231.864 us; speedup vs baseline: 1.0563x; 1.0563x over previous
//
#include <hip/hip_runtime.h>

// WKV (RWKV v4), fully fused single kernel, 2-channel threads for the
// 8-waves/SIMD register bucket.
//
// Occupancy law measured over R4-R9: resident waves/SIMD = floor(256 /
// VGPR) (VGPR 64 -> 4 waves, occ ~35%; VGPR 32 -> 8 waves, occ ~79%),
// and a 1024-thr block is a 4-wave/SIMD quantum -> 2 blocks/CU (32
// waves) requires VGPR <= 32. A 4ch/thread body needs ~52 regs and can
// never get there; this kernel uses 2 channels/thread (~30 regs).
//
// Coalescing with 8B/lane: one 1024-thr block contains TWO independent
// 512-thr scan groups (halves), covering the two 16-channel halves of a
// 32-channel tile -> the paired 64B segments of each 128B line are read
// by the SAME block (same CU, same L2), so no cross-XCD double-fetch
// (R9's failure mode; blockIdx->XCD mapping is undefined).
//
// Block: 1024 thr = 2 halves x (64 chunks x 8 cg-threads). Grid =
// B * C/32 = 512 blocks = 2 blocks/CU = 32 waves/CU if VGPR <= 32.
//   Phase 1: stream chunk (CHL=16 rows, BATCH=2, float2) -> local state.
//   Phase 2: Hillis-Steele exclusive scan over 64 chunk states in LDS
//            (6 rounds), independent per half. Operand at distance d
//            spans d*CHL steps.
//   Phase 3: re-stream chunk (L3-resident) and emit y non-temporally.
//
// u (time_first) is loaded only after the scan to keep peak regs down.
// Tripwires: VGPR > 32 impossible (cap); WRITE_SIZE > 70 MB = spill;
// FETCH_SIZE >> 140 MB = coalescing failure.
//
// All state in log2 domain (w,u,k pre-scaled by log2 e): every exponential
// is a bare v_exp_f32.

#define T_FIX  1024
#define NCH    64
#define CHL    (T_FIX / NCH)   // 16
#define BATCH  2
#define CGT    8               // cg-threads per half (16 ch / 2 ch-per-thr)
#define HALF   512
#define NTHR   1024
#define L2E    1.4426950408889634f

typedef float vfloat2 __attribute__((ext_vector_type(2)));

__device__ __forceinline__ void wkv_step2(float& aa, float& bb, float& pp,
                                          float w2, float k2, float vt)
{
    float ww2 = pp + w2;
    float q2  = fmaxf(ww2, k2);
    float e1  = exp2f(ww2 - q2);
    float e2  = exp2f(k2 - q2);
    aa = fmaf(e1, aa, e2 * vt);
    bb = fmaf(e1, bb, e2);
    pp = q2;
}

__device__ __forceinline__ void wkv_combine(float& aa, float& bb, float& pp,
                                            float ca, float cb, float cm,
                                            float w2, float Ld)
{
    // this thread's value spans Ld steps; decay the PREDECESSOR (ca,cb,cm)
    // by Ld*w and merge:  new = pred_decayed (+) own
    float ppd = fmaf(Ld, w2, cm);
    float pn  = fmaxf(ppd, pp);
    float ea  = exp2f(ppd - pn);
    float eb  = exp2f(pp - pn);
    aa = fmaf(ea, ca, eb * aa);
    bb = fmaf(ea, cb, eb * bb);
    pp = pn;
}

__global__ __launch_bounds__(NTHR, 8)
void wkv_fused(const float* __restrict__ td,
               const float* __restrict__ tf,
               const float* __restrict__ k,
               const float* __restrict__ v,
               float* __restrict__ y,
               int B, int C)
{
    __shared__ float2 a_s[NTHR];
    __shared__ float2 b_s[NTHR];
    __shared__ float2 p_s[NTHR];

    const int tid  = threadIdx.x;
    const int h    = tid & (HALF - 1);
    const int half = tid >> 9;           // which 16-ch half of the 32-ch tile
    const int cg   = h & (CGT - 1);      // channel pair within half
    const int j    = h >> 3;             // chunk index 0..63

    const int t32 = C >> 5;              // 32-channel tiles
    const int b   = blockIdx.x / t32;
    const int c   = ((blockIdx.x % t32) << 5) + (half << 4) + (cg << 1);

    float2 tdv = *(const float2*)(td + c);
    const float w20 = -__expf(tdv.x) * L2E;
    const float w21 = -__expf(tdv.y) * L2E;

    const size_t base = ((size_t)b * T_FIX + (size_t)j * CHL) * C + c;
    const float* kp = k + base;
    const float* vp = v + base;
    float*       yp = y + base;

    // ---------------- phase 1: local chunk state (streamed) ----------------
    float aa0 = 0.f, aa1 = 0.f, bb0 = 0.f, bb1 = 0.f;
    float pp0 = -1e38f, pp1 = -1e38f;

    for (int tb = 0; tb < CHL; tb += BATCH) {
        float2 k0 = *(const float2*)(kp + (size_t)(tb + 0) * C);
        float2 v0 = *(const float2*)(vp + (size_t)(tb + 0) * C);
        float2 k1 = *(const float2*)(kp + (size_t)(tb + 1) * C);
        float2 v1 = *(const float2*)(vp + (size_t)(tb + 1) * C);
        wkv_step2(aa0, bb0, pp0, w20, k0.x * L2E, v0.x);
        wkv_step2(aa1, bb1, pp1, w21, k0.y * L2E, v0.y);
        wkv_step2(aa0, bb0, pp0, w20, k1.x * L2E, v1.x);
        wkv_step2(aa1, bb1, pp1, w21, k1.y * L2E, v1.y);
    }

    a_s[tid] = make_float2(aa0, aa1);
    b_s[tid] = make_float2(bb0, bb1);
    p_s[tid] = make_float2(pp0, pp1);
    __syncthreads();

    // ---------------- phase 2: Hillis-Steele scan over chunks ----------------
    // Independent per half (neighbor tid-CGT*d stays inside the half since
    // it is only read when j >= d).
    #pragma unroll
    for (int d = 1; d < NCH; d <<= 1) {
        float2 xa, xb, xp;
        const bool act = (j >= d);
        if (act) {
            xa = a_s[tid - CGT * d];
            xb = b_s[tid - CGT * d];
            xp = p_s[tid - CGT * d];
        }
        __syncthreads();
        if (act) {
            const float Ld = (float)(d * CHL);
            wkv_combine(aa0, bb0, pp0, xa.x, xb.x, xp.x, w20, Ld);
            wkv_combine(aa1, bb1, pp1, xa.y, xb.y, xp.y, w21, Ld);
            a_s[tid] = make_float2(aa0, aa1);
            b_s[tid] = make_float2(bb0, bb1);
            p_s[tid] = make_float2(pp0, pp1);
        }
        __syncthreads();
    }

    // exclusive prefix for this chunk = inclusive value of chunk j-1
    if (j > 0) {
        float2 xa = a_s[tid - CGT];
        float2 xb = b_s[tid - CGT];
        float2 xp = p_s[tid - CGT];
        aa0 = xa.x; aa1 = xa.y;
        bb0 = xb.x; bb1 = xb.y;
        pp0 = xp.x; pp1 = xp.y;
    } else {
        aa0 = 0.f; aa1 = 0.f; bb0 = 0.f; bb1 = 0.f;
        pp0 = -1e38f; pp1 = -1e38f;
    }

    // u loaded only now (keeps peak register count down through the scan)
    float2 tfv = *(const float2*)(tf + c);
    const float u20 = tfv.x * L2E;
    const float u21 = tfv.y * L2E;

    // ---------------- phase 3: re-stream chunk, emit y ----------------
    for (int tb = 0; tb < CHL; tb += BATCH) {
        float2 k0 = *(const float2*)(kp + (size_t)(tb + 0) * C);
        float2 v0 = *(const float2*)(vp + (size_t)(tb + 0) * C);
        float2 k1 = *(const float2*)(kp + (size_t)(tb + 1) * C);
        float2 v1 = *(const float2*)(vp + (size_t)(tb + 1) * C);

        #pragma unroll
        for (int i = 0; i < 2; ++i) {
            float kx = (i == 0) ? k0.x : k1.x;
            float ky = (i == 0) ? k0.y : k1.y;
            float vx = (i == 0) ? v0.x : v1.x;
            float vy = (i == 0) ? v0.y : v1.y;

            float k2a = kx * L2E;
            float wwa = u20 + k2a;
            float qa  = fmaxf(pp0, wwa);
            float e1a = exp2f(pp0 - qa);
            float e2a = exp2f(wwa - qa);
            float ya  = __fdividef(fmaf(e1a, aa0, e2a * vx),
                                   fmaf(e1a, bb0, e2a));
            wkv_step2(aa0, bb0, pp0, w20, k2a, vx);

            float k2b = ky * L2E;
            float wwb = u21 + k2b;
            float qb  = fmaxf(pp1, wwb);
            float e1b = exp2f(pp1 - qb);
            float e2b = exp2f(wwb - qb);
            float yb  = __fdividef(fmaf(e1b, aa1, e2b * vy),
                                   fmaf(e1b, bb1, e2b));
            wkv_step2(aa1, bb1, pp1, w21, k2b, vy);

            vfloat2 yo = { ya, yb };
            __builtin_nontemporal_store(yo,
                (vfloat2*)(yp + (size_t)(tb + i) * C));
        }
    }
}

extern "C" void kernel_launch(void* const* d_in, const int* in_sizes, int n_in,
                              void* d_out, int out_size, void* d_ws, size_t ws_size,
                              hipStream_t stream)
{
    const float* td = (const float*)d_in[3];
    const float* tf = (const float*)d_in[4];
    const float* k  = (const float*)d_in[5];
    const float* v  = (const float*)d_in[6];
    float*       y  = (float*)d_out;

    const int C   = in_sizes[3];
    const int BTC = in_sizes[5];
    const int B   = BTC / (T_FIX * C);

    const int grid = B * (C >> 5);   // 512 for B=8, C=2048
    wkv_fused<<<grid, NTHR, 0, stream>>>(td, tf, k, v, y, B, C);
}

// Round 12
// 216.136 us; speedup vs baseline: 1.1332x; 1.0728x over previous
//
#include <hip/hip_runtime.h>

// WKV (RWKV v4), fused single kernel, FORCED 8-row load bursts.
//
// Series conclusion (R4-R10): occupancy is NOT the limiter (occ 32->79%
// never helped; effective BW pinned ~2.1-2.9 TB/s in all configs). The
// limiter is per-wave latency exposures: the compiler dribbles staged
// loads 2-3 rows at a time (R4: VGPR 52 chosen under cap 128), giving
// ~5-6 sequential memory round-trips per phase.
//
// Fix: asm-pin the staging registers. Loading 8 rows of k,v (16 float4)
// and consuming them in an empty `asm volatile (:: "v"(..))` forces all
// 16 loads issued + ONE vmcnt wait per burst. 2 bursts per phase.
// (R11 compile lesson: "v" constraints need native clang vector types,
// not HIP's float4 class -> stage into ext_vector_type(4).)
// Geometry is round-4's proven no-spill shape:
//   512 thr = 64 chunks x 8 cg-threads, CTILE=32 (128B wave segments),
//   CHL=16, grid = B*C/32 = 512 blocks, __launch_bounds__(512,2) cap 128.
//
// Phase 1: 2 forced bursts (HBM, ~900cy each) -> local chunk state.
// Phase 2: Hillis-Steele exclusive scan over 64 chunk states in LDS.
// Phase 3: 2 forced bursts (L2/L3-hit, ~200cy) -> emit y (nt stores).
//
// Tripwires: VGPR <= 64 -> pin failed (void experiment);
//            WRITE > 66MB -> spill; FETCH >> 140MB -> coalescing broke.
//
// All state in log2 domain (w,u,k pre-scaled by log2 e): every
// exponential is a bare v_exp_f32.

#define T_FIX  1024
#define NCH    64
#define CHL    (T_FIX / NCH)   // 16
#define HB     8               // rows per forced burst
#define CTILE  32
#define CGT    (CTILE / 4)     // 8
#define NTHR   (NCH * CGT)     // 512
#define L2E    1.4426950408889634f

typedef float vfloat4 __attribute__((ext_vector_type(4)));

// Force all 8 vfloat4s of an array to be materialized in VGPRs here.
#define PIN8(arr) asm volatile("" :: "v"(arr[0]), "v"(arr[1]), "v"(arr[2]), \
    "v"(arr[3]), "v"(arr[4]), "v"(arr[5]), "v"(arr[6]), "v"(arr[7]))

__device__ __forceinline__ void wkv_step2(float& aa, float& bb, float& pp,
                                          float w2, float k2, float vt)
{
    float ww2 = pp + w2;
    float q2  = fmaxf(ww2, k2);
    float e1  = exp2f(ww2 - q2);
    float e2  = exp2f(k2 - q2);
    aa = fmaf(e1, aa, e2 * vt);
    bb = fmaf(e1, bb, e2);
    pp = q2;
}

__global__ __launch_bounds__(NTHR, 2)
void wkv_fused(const float* __restrict__ td,
               const float* __restrict__ tf,
               const float* __restrict__ k,
               const float* __restrict__ v,
               float* __restrict__ y,
               int B, int C)
{
    __shared__ float4 a_s[NTHR];
    __shared__ float4 b_s[NTHR];
    __shared__ float4 p_s[NTHR];

    const int tid = threadIdx.x;
    const int cg  = tid & (CGT - 1);     // channel group within tile
    const int j   = tid >> 3;            // chunk index 0..63

    const int tiles = C / CTILE;
    const int b  = blockIdx.x / tiles;
    const int c  = (blockIdx.x % tiles) * CTILE + (cg << 2);

    float4 tdv = *(const float4*)(td + c);
    float4 tfv = *(const float4*)(tf + c);
    float w2[4] = { -__expf(tdv.x) * L2E, -__expf(tdv.y) * L2E,
                    -__expf(tdv.z) * L2E, -__expf(tdv.w) * L2E };
    float u2[4] = { tfv.x * L2E, tfv.y * L2E, tfv.z * L2E, tfv.w * L2E };

    const size_t base = ((size_t)b * T_FIX + (size_t)j * CHL) * C + c;
    const float* kp = k + base;
    const float* vp = v + base;
    float*       yp = y + base;

    // ---------------- phase 1: local chunk state, 2 forced bursts ----------
    float aa[4] = {0.f, 0.f, 0.f, 0.f};
    float bb[4] = {0.f, 0.f, 0.f, 0.f};
    float pp[4] = {-1e38f, -1e38f, -1e38f, -1e38f};

    for (int tb = 0; tb < CHL; tb += HB) {
        vfloat4 kb[HB], vb[HB];
        #pragma unroll
        for (int i = 0; i < HB; ++i) {
            kb[i] = *(const vfloat4*)(kp + (size_t)(tb + i) * C);
            vb[i] = *(const vfloat4*)(vp + (size_t)(tb + i) * C);
        }
        PIN8(kb);
        PIN8(vb);
        #pragma unroll
        for (int i = 0; i < HB; ++i) {
            #pragma unroll
            for (int cc = 0; cc < 4; ++cc)
                wkv_step2(aa[cc], bb[cc], pp[cc], w2[cc],
                          kb[i][cc] * L2E, vb[i][cc]);
        }
    }

    a_s[tid] = make_float4(aa[0], aa[1], aa[2], aa[3]);
    b_s[tid] = make_float4(bb[0], bb[1], bb[2], bb[3]);
    p_s[tid] = make_float4(pp[0], pp[1], pp[2], pp[3]);
    __syncthreads();

    // ---------------- phase 2: Hillis-Steele scan over chunks ----------------
    #pragma unroll
    for (int d = 1; d < NCH; d <<= 1) {
        float pa[4], pb[4], pm[4];
        const bool act = (j >= d);
        if (act) {
            float4 xa = a_s[tid - CGT * d];
            float4 xb = b_s[tid - CGT * d];
            float4 xp = p_s[tid - CGT * d];
            pa[0] = xa.x; pa[1] = xa.y; pa[2] = xa.z; pa[3] = xa.w;
            pb[0] = xb.x; pb[1] = xb.y; pb[2] = xb.z; pb[3] = xb.w;
            pm[0] = xp.x; pm[1] = xp.y; pm[2] = xp.z; pm[3] = xp.w;
        }
        __syncthreads();
        if (act) {
            const float Ld = (float)(d * CHL);   // steps the own value spans
            #pragma unroll
            for (int cc = 0; cc < 4; ++cc) {
                float ppd = fmaf(Ld, w2[cc], pm[cc]);   // decay predecessor
                float pn  = fmaxf(ppd, pp[cc]);
                float ea  = exp2f(ppd - pn);
                float eb  = exp2f(pp[cc] - pn);
                aa[cc] = fmaf(ea, pa[cc], eb * aa[cc]);
                bb[cc] = fmaf(ea, pb[cc], eb * bb[cc]);
                pp[cc] = pn;
            }
            a_s[tid] = make_float4(aa[0], aa[1], aa[2], aa[3]);
            b_s[tid] = make_float4(bb[0], bb[1], bb[2], bb[3]);
            p_s[tid] = make_float4(pp[0], pp[1], pp[2], pp[3]);
        }
        __syncthreads();
    }

    // exclusive prefix for this chunk = inclusive value of chunk j-1
    if (j > 0) {
        float4 xa = a_s[tid - CGT];
        float4 xb = b_s[tid - CGT];
        float4 xp = p_s[tid - CGT];
        aa[0] = xa.x; aa[1] = xa.y; aa[2] = xa.z; aa[3] = xa.w;
        bb[0] = xb.x; bb[1] = xb.y; bb[2] = xb.z; bb[3] = xb.w;
        pp[0] = xp.x; pp[1] = xp.y; pp[2] = xp.z; pp[3] = xp.w;
    } else {
        #pragma unroll
        for (int cc = 0; cc < 4; ++cc) { aa[cc] = 0.f; bb[cc] = 0.f; pp[cc] = -1e38f; }
    }

    // ---------------- phase 3: emit y, 2 forced bursts (cache-hit) ---------
    for (int tb = 0; tb < CHL; tb += HB) {
        vfloat4 kb[HB], vb[HB];
        #pragma unroll
        for (int i = 0; i < HB; ++i) {
            kb[i] = *(const vfloat4*)(kp + (size_t)(tb + i) * C);
            vb[i] = *(const vfloat4*)(vp + (size_t)(tb + i) * C);
        }
        PIN8(kb);
        PIN8(vb);
        #pragma unroll
        for (int i = 0; i < HB; ++i) {
            float ya[4];
            #pragma unroll
            for (int cc = 0; cc < 4; ++cc) {
                float k2 = kb[i][cc] * L2E;
                float vt = vb[i][cc];
                float ww = u2[cc] + k2;
                float q  = fmaxf(pp[cc], ww);
                float e1 = exp2f(pp[cc] - q);
                float e2 = exp2f(ww - q);
                ya[cc] = __fdividef(fmaf(e1, aa[cc], e2 * vt),
                                    fmaf(e1, bb[cc], e2));
                wkv_step2(aa[cc], bb[cc], pp[cc], w2[cc], k2, vt);
            }
            vfloat4 yo = { ya[0], ya[1], ya[2], ya[3] };
            __builtin_nontemporal_store(yo, (vfloat4*)(yp + (size_t)(tb + i) * C));
        }
    }
}

extern "C" void kernel_launch(void* const* d_in, const int* in_sizes, int n_in,
                              void* d_out, int out_size, void* d_ws, size_t ws_size,
                              hipStream_t stream)
{
    const float* td = (const float*)d_in[3];
    const float* tf = (const float*)d_in[4];
    const float* k  = (const float*)d_in[5];
    const float* v  = (const float*)d_in[6];
    float*       y  = (float*)d_out;

    const int C   = in_sizes[3];
    const int BTC = in_sizes[5];
    const int B   = BTC / (T_FIX * C);

    const int grid = B * (C / CTILE);   // 512 for B=8, C=2048
    wkv_fused<<<grid, NTHR, 0, stream>>>(td, tf, k, v, y, B, C);
}